// Round 6
// baseline (145.969 us; speedup 1.0000x reference)
//
#include <hip/hip_runtime.h>

typedef __bf16 bf16x8 __attribute__((ext_vector_type(8)));
typedef __bf16 bf16x4 __attribute__((ext_vector_type(4)));
typedef float  f32x4  __attribute__((ext_vector_type(4)));
typedef float  f32x16 __attribute__((ext_vector_type(16)));
typedef unsigned u32x2 __attribute__((ext_vector_type(2)));
typedef unsigned u32x4 __attribute__((ext_vector_type(4)));

#define T_SEQ 2048
#define NH    16
#define HD    64
#define EMB   1024
#define BATCH 2
// 1/sqrt(HD) * log2(e) — softmax in base 2
#define QSCALE 0.18033688f

__device__ __forceinline__ void gload_lds16(const void* g, void* lds) {
  __builtin_amdgcn_global_load_lds(
      (__attribute__((address_space(1))) void*)(g),
      (__attribute__((address_space(3))) void*)(lds), 16, 0, 0);
}

__device__ __forceinline__ f32x16 mfma32(bf16x8 a, bf16x8 b, f32x16 c) {
  return __builtin_amdgcn_mfma_f32_32x32x16_bf16(a, b, c, 0, 0, 0);
}

__device__ __forceinline__ f32x4 mfma16(bf16x8 a, bf16x8 b, f32x4 c) {
  return __builtin_amdgcn_mfma_f32_16x16x32_bf16(a, b, c, 0, 0, 0);
}

__device__ __forceinline__ unsigned cvtpk(float lo, float hi) {
  unsigned short a = __builtin_bit_cast(unsigned short, (__bf16)lo);
  unsigned short b = __builtin_bit_cast(unsigned short, (__bf16)hi);
  return (unsigned)a | ((unsigned)b << 16);
}

// ---- fp32 -> bf16 straight convert ----
__global__ __launch_bounds__(256) void cvt_bf16(const float* __restrict__ in,
                                                __bf16* __restrict__ out, int n) {
  int i = (blockIdx.x * 256 + threadIdx.x) * 8;
  if (i >= n) return;
  f32x4 a = *(const f32x4*)(in + i);
  f32x4 b = *(const f32x4*)(in + i + 4);
  bf16x8 v;
  v[0] = (__bf16)a[0]; v[1] = (__bf16)a[1]; v[2] = (__bf16)a[2]; v[3] = (__bf16)a[3];
  v[4] = (__bf16)b[0]; v[5] = (__bf16)b[1]; v[6] = (__bf16)b[2]; v[7] = (__bf16)b[3];
  *(bf16x8*)(out + i) = v;
}

// ---- fp32 [rows][cols] -> bf16 [cols][rows] ----
__global__ __launch_bounds__(256) void transpose_cvt(const float* __restrict__ in,
                                                     __bf16* __restrict__ out,
                                                     int rows, int cols) {
  __shared__ float tile[32][33];
  int c0 = blockIdx.x * 32, r0 = blockIdx.y * 32;
  int tx = threadIdx.x & 31, ty = threadIdx.x >> 5;
#pragma unroll
  for (int j = 0; j < 32; j += 8)
    tile[ty + j][tx] = in[(size_t)(r0 + ty + j) * cols + c0 + tx];
  __syncthreads();
#pragma unroll
  for (int j = 0; j < 32; j += 8)
    out[(size_t)(c0 + ty + j) * rows + r0 + tx] = (__bf16)tile[tx][ty + j];
}

// ======================================================================
// QKV GEMM: 256x256 tile, BK=64, 8 waves (2M x 4N), 8-phase counted-vmcnt
// schedule (T3+T4+T5). C[M=4096, N=3072] = A[M,K=1024] * Bt[N,K]^T with
// QKV scatter epilogue.
// LDS swizzle (both sides, rule 21): LDS[row][u] = G[row][u ^ (row&7)],
// 16B units, linear gload_lds dest + pre-swizzled source + swizzled read.
// Staging per tile t: P1=B(t+1)h0, P2=B(t+1)h1, P3=A(t+2)h0, P4=A(t+2)h1.
// vmcnt(4) once per K-tile (A(t+1)'s 4 loads stay in flight).
// ======================================================================
__global__ __launch_bounds__(512, 2) void gemm_qkv(
    const __bf16* __restrict__ A, const __bf16* __restrict__ Bt,
    __bf16* __restrict__ Qo, __bf16* __restrict__ Ko, __bf16* __restrict__ Vt) {
  constexpr int K = 1024, NT = K / 64;
  __shared__ alignas(16) __bf16 sA[2][256 * 64];
  __shared__ alignas(16) __bf16 sB[2][256 * 64];
  const int tid = threadIdx.x;
  const int w = tid >> 6, l = tid & 63;
  const int wr = w >> 2, wc = w & 3;           // wave grid 2M x 4N
  const int lc = l & 15, lu = l >> 4;
  const int m0 = blockIdx.y * 256, n0 = blockIdx.x * 256;

  const int srow = tid >> 3;                   // 0..63
  const int gsw = ((tid & 7) ^ (srow & 7)) * 8;  // pre-swizzled source col (elems)

  f32x4 acc[8][4] = {};

  // stage one 128-row half (2 x gload_lds16 per thread)
  auto stageA = [&](int buf, int t, int h) {
    const __bf16* src = A + (size_t)(m0 + h * 128) * K + t * 64 + gsw;
    __bf16* dst = &sA[buf][(h * 128 + w * 8) * 64];
#pragma unroll
    for (int j = 0; j < 2; ++j)
      gload_lds16(src + (size_t)(j * 64 + srow) * K, dst + j * 64 * 64);
  };
  auto stageB = [&](int buf, int t, int h) {
    const __bf16* src = Bt + (size_t)(n0 + h * 128) * K + t * 64 + gsw;
    __bf16* dst = &sB[buf][(h * 128 + w * 8) * 64];
#pragma unroll
    for (int j = 0; j < 2; ++j)
      gload_lds16(src + (size_t)(j * 64 + srow) * K, dst + j * 64 * 64);
  };

  auto rdA = [&](int buf, int m, int kk) -> bf16x8 {
    int row = wr * 128 + m * 16 + lc;
    return *(const bf16x8*)(&sA[buf][row * 64 + (((kk << 2) + lu) ^ (lc & 7)) * 8]);
  };
  auto rdB = [&](int buf, int n, int kk) -> bf16x8 {
    int row = wc * 64 + n * 16 + lc;
    return *(const bf16x8*)(&sB[buf][row * 64 + (((kk << 2) + lu) ^ (lc & 7)) * 8]);
  };

  // prologue: A(0), B(0), A(1); wait for tile 0, keep A(1) in flight
  stageA(0, 0, 0); stageA(0, 0, 1);
  stageB(0, 0, 0); stageB(0, 0, 1);
  stageA(1, 1, 0); stageA(1, 1, 1);
  asm volatile("s_waitcnt vmcnt(4)" ::: "memory");
  __builtin_amdgcn_s_barrier();
  __builtin_amdgcn_sched_barrier(0);

#pragma unroll 2
  for (int t = 0; t < NT; ++t) {
    const int cb = t & 1;
    bf16x8 af0[4][2], af1[4][2], b0[2][2], b1[2][2];

    // ---------------- phase 1: M0-3 x N0-1 ----------------
#pragma unroll
    for (int m = 0; m < 4; ++m) { af0[m][0] = rdA(cb, m, 0); af0[m][1] = rdA(cb, m, 1); }
#pragma unroll
    for (int n = 0; n < 2; ++n) { b0[n][0] = rdB(cb, n, 0); b0[n][1] = rdB(cb, n, 1); }
    if (t + 1 < NT) stageB(cb ^ 1, t + 1, 0);
    __builtin_amdgcn_s_barrier();
    asm volatile("s_waitcnt lgkmcnt(0)" ::: "memory");
    __builtin_amdgcn_sched_barrier(0);
    __builtin_amdgcn_s_setprio(1);
#pragma unroll
    for (int m = 0; m < 4; ++m)
#pragma unroll
      for (int n = 0; n < 2; ++n) {
        acc[m][n] = mfma16(af0[m][0], b0[n][0], acc[m][n]);
        acc[m][n] = mfma16(af0[m][1], b0[n][1], acc[m][n]);
      }
    __builtin_amdgcn_s_setprio(0);
    __builtin_amdgcn_s_barrier();
    __builtin_amdgcn_sched_barrier(0);

    // ---------------- phase 2: M4-7 x N0-1 ----------------
#pragma unroll
    for (int m = 0; m < 4; ++m) { af1[m][0] = rdA(cb, 4 + m, 0); af1[m][1] = rdA(cb, 4 + m, 1); }
    if (t + 1 < NT) stageB(cb ^ 1, t + 1, 1);
    __builtin_amdgcn_s_barrier();
    asm volatile("s_waitcnt lgkmcnt(0)" ::: "memory");
    __builtin_amdgcn_sched_barrier(0);
    __builtin_amdgcn_s_setprio(1);
#pragma unroll
    for (int m = 0; m < 4; ++m)
#pragma unroll
      for (int n = 0; n < 2; ++n) {
        acc[4 + m][n] = mfma16(af1[m][0], b0[n][0], acc[4 + m][n]);
        acc[4 + m][n] = mfma16(af1[m][1], b0[n][1], acc[4 + m][n]);
      }
    __builtin_amdgcn_s_setprio(0);
    __builtin_amdgcn_s_barrier();
    __builtin_amdgcn_sched_barrier(0);

    // ---------------- phase 3: M4-7 x N2-3 ----------------
#pragma unroll
    for (int n = 0; n < 2; ++n) { b1[n][0] = rdB(cb, 2 + n, 0); b1[n][1] = rdB(cb, 2 + n, 1); }
    if (t + 2 < NT) stageA(cb, t + 2, 0);
    __builtin_amdgcn_s_barrier();
    asm volatile("s_waitcnt lgkmcnt(0)" ::: "memory");
    __builtin_amdgcn_sched_barrier(0);
    __builtin_amdgcn_s_setprio(1);
#pragma unroll
    for (int m = 0; m < 4; ++m)
#pragma unroll
      for (int n = 0; n < 2; ++n) {
        acc[4 + m][2 + n] = mfma16(af1[m][0], b1[n][0], acc[4 + m][2 + n]);
        acc[4 + m][2 + n] = mfma16(af1[m][1], b1[n][1], acc[4 + m][2 + n]);
      }
    __builtin_amdgcn_s_setprio(0);
    __builtin_amdgcn_s_barrier();
    __builtin_amdgcn_sched_barrier(0);

    // ---------------- phase 4: M0-3 x N2-3 ----------------
    if (t + 2 < NT) stageA(cb, t + 2, 1);
    __builtin_amdgcn_s_barrier();
    __builtin_amdgcn_sched_barrier(0);
    __builtin_amdgcn_s_setprio(1);
#pragma unroll
    for (int m = 0; m < 4; ++m)
#pragma unroll
      for (int n = 0; n < 2; ++n) {
        acc[m][2 + n] = mfma16(af0[m][0], b1[n][0], acc[m][2 + n]);
        acc[m][2 + n] = mfma16(af0[m][1], b1[n][1], acc[m][2 + n]);
      }
    __builtin_amdgcn_s_setprio(0);
    if (t + 2 < NT) { asm volatile("s_waitcnt vmcnt(4)" ::: "memory"); }
    else            { asm volatile("s_waitcnt vmcnt(0)" ::: "memory"); }
    __builtin_amdgcn_s_barrier();
    __builtin_amdgcn_sched_barrier(0);
  }

  // ---- QKV scatter epilogue; C/D layout: row=(l>>4)*4+r, col=l&15 ----
#pragma unroll
  for (int mf = 0; mf < 8; ++mf) {
#pragma unroll
    for (int nf = 0; nf < 4; ++nf) {
#pragma unroll
      for (int r = 0; r < 4; ++r) {
        int mg = m0 + wr * 128 + mf * 16 + lu * 4 + r;
        int ng = n0 + wc * 64 + nf * 16 + lc;
        float v = acc[mf][nf][r];
        int part = ng >> 10;
        int h = (ng >> 6) & 15;
        int d = ng & 63;
        int b = mg >> 11;
        int tq = mg & 2047;
        if (part == 0) {
          Qo[(((size_t)(b * NH + h)) * T_SEQ + tq) * HD + d] = (__bf16)(v * QSCALE);
        } else if (part == 1) {
          Ko[(((size_t)(b * NH + h)) * T_SEQ + tq) * HD + d] = (__bf16)v;
        } else {
          Vt[(((size_t)(b * NH + h)) * HD + d) * T_SEQ + tq] = (__bf16)v;
        }
      }
    }
  }
}

// ---- proj gemm: C[M,N] = A[M,K] * Bt[N,K]^T + bias, 128x128, dbuf ----
__global__ __launch_bounds__(256) void gemm_proj(
    const __bf16* __restrict__ A, const __bf16* __restrict__ Bt, int K,
    const float* __restrict__ bias, float* __restrict__ Cout) {
  __shared__ alignas(16) __bf16 sA[2][128 * 32];
  __shared__ alignas(16) __bf16 sB[2][128 * 32];
  const int tid = threadIdx.x;
  const int w = tid >> 6, l = tid & 63;
  const int m0 = blockIdx.y * 128, n0 = blockIdx.x * 128;
  const int lc = l & 15, lu = l >> 4;
  const int mw = (w >> 1) * 64, nw = (w & 1) * 64;
  const int rA = l >> 2;
  const int usw = (((l & 3) ^ ((rA >> 1) & 3))) * 8;
  const int rsw = (lu ^ ((lc >> 1) & 3)) * 8;

  f32x4 acc[4][4] = {};

  auto stage = [&](int buf, int kt) {
#pragma unroll
    for (int i = 0; i < 2; ++i) {
      int rr = (w * 2 + i) * 16;
      gload_lds16(A  + (size_t)(m0 + rr + rA) * K + kt + usw, &sA[buf][rr * 32]);
      gload_lds16(Bt + (size_t)(n0 + rr + rA) * K + kt + usw, &sB[buf][rr * 32]);
    }
  };

  stage(0, 0);
  asm volatile("s_waitcnt vmcnt(0)" ::: "memory");
  __syncthreads();

  int buf = 0;
  for (int kt = 0; kt < K; kt += 32) {
    if (kt + 32 < K) stage(buf ^ 1, kt + 32);
    bf16x8 af[4], bfr[4];
#pragma unroll
    for (int f = 0; f < 4; ++f) {
      af[f]  = *(const bf16x8*)(&sA[buf][(mw + f * 16 + lc) * 32 + rsw]);
      bfr[f] = *(const bf16x8*)(&sB[buf][(nw + f * 16 + lc) * 32 + rsw]);
    }
#pragma unroll
    for (int mf = 0; mf < 4; ++mf)
#pragma unroll
      for (int nf = 0; nf < 4; ++nf)
        acc[mf][nf] = mfma16(af[mf], bfr[nf], acc[mf][nf]);
    asm volatile("s_waitcnt vmcnt(0)" ::: "memory");
    __syncthreads();
    buf ^= 1;
  }

#pragma unroll
  for (int mf = 0; mf < 4; ++mf)
#pragma unroll
    for (int nf = 0; nf < 4; ++nf)
#pragma unroll
      for (int r = 0; r < 4; ++r) {
        int mg = m0 + mw + mf * 16 + lu * 4 + r;
        int ng = n0 + nw + nf * 16 + lc;
        Cout[(size_t)mg * EMB + ng] = acc[mf][nf][r] + bias[ng];
      }
}

// ---- LDS fragment read with XOR swizzle on 16B units ----
__device__ __forceinline__ bf16x8 lfrag(const __bf16* b, int row, int u) {
  return *(const bf16x8*)(b + row * 64 + ((u ^ (row & 7)) << 3));
}

// ---- causal mask on S^T (rows=k, col=q per lane) ----
__device__ __forceinline__ void cmask(f32x16& s0, f32x16& s1, int k0, int hi, int q) {
#pragma unroll
  for (int r = 0; r < 16; ++r) {
    int kk = k0 + 4 * hi + (r & 3) + 8 * (r >> 2);
    if (kk > q) s0[r] = -1e30f;
    if (kk + 32 > q) s1[r] = -1e30f;
  }
}

// ---- in-register online softmax + P packing (T12/T13) ----
__device__ __forceinline__ void softmax_pack(
    f32x16& s0, f32x16& s1, f32x16& o0, f32x16& o1,
    float& m, float& ls, u32x4 (&pf)[4]) {
  float mx[16];
#pragma unroll
  for (int r = 0; r < 16; ++r) mx[r] = fmaxf(s0[r], s1[r]);
#pragma unroll
  for (int st = 8; st > 0; st >>= 1)
#pragma unroll
    for (int r = 0; r < 16; ++r) if (r < st) mx[r] = fmaxf(mx[r], mx[r + st]);
  float pmax = fmaxf(mx[0], __shfl_xor(mx[0], 32));
  if (!__all(pmax <= m + 8.0f)) {       // defer-max rescale
    float mn = fmaxf(m, pmax);
    float al = __builtin_amdgcn_exp2f(m - mn);
    m = mn;
    ls *= al;
#pragma unroll
    for (int r = 0; r < 16; ++r) { o0[r] *= al; o1[r] *= al; }
  }
  float ps = 0.f;
  f32x16 p0, p1;
#pragma unroll
  for (int r = 0; r < 16; ++r) {
    p0[r] = __builtin_amdgcn_exp2f(s0[r] - m); ps += p0[r];
    p1[r] = __builtin_amdgcn_exp2f(s1[r] - m); ps += p1[r];
  }
  ps += __shfl_xor(ps, 32);
  ls += ps;
#pragma unroll
  for (int kt = 0; kt < 2; ++kt) {
    const f32x16& p = kt ? p1 : p0;
#pragma unroll
    for (int kh = 0; kh < 2; ++kh) {
      unsigned c01 = cvtpk(p[kh * 8 + 0], p[kh * 8 + 1]);
      unsigned c23 = cvtpk(p[kh * 8 + 2], p[kh * 8 + 3]);
      unsigned c45 = cvtpk(p[kh * 8 + 4], p[kh * 8 + 5]);
      unsigned c67 = cvtpk(p[kh * 8 + 6], p[kh * 8 + 7]);
      u32x2 a = __builtin_amdgcn_permlane32_swap(c01, c45, false, false);
      u32x2 c = __builtin_amdgcn_permlane32_swap(c23, c67, false, false);
      u32x4 r; r[0] = a[0]; r[1] = c[0]; r[2] = a[1]; r[3] = c[1];
      pf[kt * 2 + kh] = r;
    }
  }
}

__device__ __forceinline__ void dump_state(float* mo, float* mm, int reg, int l,
                                           const f32x16& o0, const f32x16& o1,
                                           float m, float ls) {
  float* po = mo + reg * 2048 + l;
#pragma unroll
  for (int r = 0; r < 16; ++r) { po[r * 64] = o0[r]; po[(16 + r) * 64] = o1[r]; }
  mm[reg * 128 + l] = m;
  mm[reg * 128 + 64 + l] = ls;
}

__device__ __forceinline__ void merge_write(const float* mo, const float* mm,
                                            int reg, int l, int hi,
                                            const f32x16& o0, const f32x16& o1,
                                            float m, float ls,
                                            __bf16* O, size_t rowbase) {
  float m1 = mm[reg * 128 + l];
  float l1 = mm[reg * 128 + 64 + l];
  float mn = fmaxf(m, m1);
  float a0 = __builtin_amdgcn_exp2f(m - mn);
  float a1 = __builtin_amdgcn_exp2f(m1 - mn);
  float inv = 1.f / (ls * a0 + l1 * a1);
  const float* po = mo + reg * 2048 + l;
#pragma unroll
  for (int dt = 0; dt < 2; ++dt) {
    const f32x16& ov = dt ? o1 : o0;
#pragma unroll
    for (int rg = 0; rg < 4; ++rg) {
      bf16x4 vv;
#pragma unroll
      for (int j = 0; j < 4; ++j) {
        int r = rg * 4 + j;
        float oth = po[(dt * 16 + r) * 64];
        vv[j] = (__bf16)((ov[r] * a0 + oth * a1) * inv);
      }
      int d = dt * 32 + rg * 8 + 4 * hi;
      *(bf16x4*)(O + rowbase + d) = vv;
    }
  }
}

// ---- causal flash attention: paired chunks (x, 31-x), k-parity split ----
__global__ __launch_bounds__(256, 2) void attn(
    const __bf16* __restrict__ Q,   // [BH][T][D] pre-scaled by QSCALE
    const __bf16* __restrict__ K,   // [BH][T][D]
    const __bf16* __restrict__ Vt,  // [BH][D][T]
    __bf16* __restrict__ O) {       // [B*T][EMB]
  __shared__ alignas(16) __bf16 sKV[8][64 * 64];   // [0..3] K slots, [4..7] V slots
  __shared__ alignas(16) float mls[4 * 2 * 64];    // merge m/ls scratch

  const int x = blockIdx.x, bh = blockIdx.y;
  const int tid = threadIdx.x, w = tid >> 6, l = tid & 63;
  const int lq = l & 31, hi = l >> 5;
  const int gc = w & 1;   // compute parity / staged-tile parity
  const int s  = w >> 1;  // subtile / staging kind (0=K, 1=V)

  const __bf16* Qh = Q + (size_t)bh * T_SEQ * HD;
  const __bf16* Kh = K + (size_t)bh * T_SEQ * HD;
  const __bf16* Vh = Vt + (size_t)bh * HD * T_SEQ;

  const int qL = x * 64 + s * 32;
  const int qH = (31 - x) * 64 + s * 32;
  const int nt = 32 - x;
  const int nsup = (nt + 1) >> 1;

  bf16x8 qfL[4], qfH[4];
#pragma unroll
  for (int dc = 0; dc < 4; ++dc) {
    qfL[dc] = *(const bf16x8*)(Qh + (size_t)(qL + lq) * HD + dc * 16 + hi * 8);
    qfH[dc] = *(const bf16x8*)(Qh + (size_t)(qH + lq) * HD + dc * 16 + hi * 8);
  }

  f32x16 oL0 = {}, oL1 = {}, oH0 = {}, oH1 = {};
  float mL = -1e30f, lsL = 0.f, mH = -1e30f, lsH = 0.f;

  const int r8 = l >> 3;
  const int uswE = ((l & 7) ^ r8) << 3;   // swizzled source unit, bf16 elems

  auto stage = [&](int buf, int ss) {
    int t = 2 * ss + gc;
    if (t > 31) t = 31;                   // clamp (data unused, stays in range)
    int k0s = t * 64;
    __bf16* dst = &sKV[s * 4 + buf * 2 + gc][0];
    if (s == 0) {
#pragma unroll
      for (int i = 0; i < 8; ++i)
        gload_lds16(Kh + (size_t)(k0s + i * 8 + r8) * HD + uswE, dst + i * 512);
    } else {
#pragma unroll
      for (int i = 0; i < 8; ++i)
        gload_lds16(Vh + (size_t)(i * 8 + r8) * T_SEQ + k0s + uswE, dst + i * 512);
    }
  };

  stage(0, 0);
  asm volatile("s_waitcnt vmcnt(0)" ::: "memory");
  __syncthreads();

  int buf = 0;
  for (int ss = 0; ss < nsup; ++ss) {
    if (ss + 1 < nsup) stage(buf ^ 1, ss + 1);
    const int tg = 2 * ss + gc;
    const bool doH = (tg < nt);
    const bool doL = (tg <= x);
    if (doH) {
      const __bf16* sKb = &sKV[buf * 2 + gc][0];
      const __bf16* sVb = &sKV[4 + buf * 2 + gc][0];
      f32x16 sH0 = {}, sH1 = {}, sL0 = {}, sL1 = {};
#pragma unroll
      for (int dc = 0; dc < 4; ++dc) {
        bf16x8 kf0 = lfrag(sKb, lq, dc * 2 + hi);
        bf16x8 kf1 = lfrag(sKb, 32 + lq, dc * 2 + hi);
        sH0 = mfma32(kf0, qfH[dc], sH0);
        sH1 = mfma32(kf1, qfH[dc], sH1);
        if (doL) {
          sL0 = mfma32(kf0, qfL[dc], sL0);
          sL1 = mfma32(kf1, qfL[dc], sL1);
        }
      }
      const int k0 = tg * 64;
      if (tg == nt - 1) cmask(sH0, sH1, k0, hi, qH + lq);
      u32x4 pfH[4], pfL[4];
      softmax_pack(sH0, sH1, oH0, oH1, mH, lsH, pfH);
      if (doL) {
        if (tg == x) cmask(sL0, sL1, k0, hi, qL + lq);
        softmax_pack(sL0, sL1, oL0, oL1, mL, lsL, pfL);
      }
#pragma unroll
      for (int ks = 0; ks < 4; ++ks) {
        bf16x8 vf0 = lfrag(sVb, lq, ks * 2 + hi);
        bf16x8 vf1 = lfrag(sVb, 32 + lq, ks * 2 + hi);
        bf16x8 pH = __builtin_bit_cast(bf16x8, pfH[ks]);
        oH0 = mfma32(vf0, pH, oH0);
        oH1 = mfma32(vf1, pH, oH1);
        if (doL) {
          bf16x8 pL = __builtin_bit_cast(bf16x8, pfL[ks]);
          oL0 = mfma32(vf0, pL, oL0);
          oL1 = mfma32(vf1, pL, oL1);
        }
      }
    }
    asm volatile("s_waitcnt vmcnt(0)" ::: "memory");
    __syncthreads();
    buf ^= 1;
  }

  // ---- cross-group merge (odd parity dumps, even parity merges + stores) ----
  float* mo = (float*)&sKV[0][0];   // aliases sKV after compute
  if (gc == 1) {
    dump_state(mo, mls, s * 2 + 0, l, oH0, oH1, mH, lsH);
    dump_state(mo, mls, s * 2 + 1, l, oL0, oL1, mL, lsL);
  }
  __syncthreads();
  if (gc == 0) {
    const int b = bh >> 4, h = bh & 15;
    size_t rowH = (size_t)(b * T_SEQ + qH + lq) * EMB + h * HD;
    size_t rowL = (size_t)(b * T_SEQ + qL + lq) * EMB + h * HD;
    merge_write(mo, mls, s * 2 + 0, l, hi, oH0, oH1, mH, lsH, O, rowH);
    merge_write(mo, mls, s * 2 + 1, l, hi, oL0, oL1, mL, lsL, O, rowL);
  }
}

extern "C" void kernel_launch(void* const* d_in, const int* in_sizes, int n_in,
                              void* d_out, int out_size, void* d_ws, size_t ws_size,
                              hipStream_t stream) {
  const float* x      = (const float*)d_in[0];
  const float* w_qkv  = (const float*)d_in[1];
  const float* w_proj = (const float*)d_in[2];
  const float* b_proj = (const float*)d_in[3];
  float* out = (float*)d_out;

  char* ws = (char*)d_ws;
  __bf16* xb     = (__bf16*)(ws);                     // 8 MiB
  __bf16* wqkvT  = (__bf16*)(ws + (8u  << 20));       // 6 MiB
  __bf16* wprojT = (__bf16*)(ws + (14u << 20));       // 2 MiB
  __bf16* Qw     = (__bf16*)(ws + (16u << 20));       // 8 MiB
  __bf16* Kw     = (__bf16*)(ws + (24u << 20));       // 8 MiB
  __bf16* Vw     = (__bf16*)(ws + (32u << 20));       // 8 MiB
  __bf16* Ow     = xb;                                // reuse after QKV GEMM

  cvt_bf16<<<2048, 256, 0, stream>>>(x, xb, 4096 * 1024);
  transpose_cvt<<<dim3(3072 / 32, 1024 / 32), 256, 0, stream>>>(w_qkv, wqkvT, 1024, 3072);
  transpose_cvt<<<dim3(1024 / 32, 1024 / 32), 256, 0, stream>>>(w_proj, wprojT, 1024, 1024);

  gemm_qkv<<<dim3(3072 / 256, 4096 / 256), 512, 0, stream>>>(
      xb, wqkvT, Qw, Kw, Vw);

  attn<<<dim3(16, BATCH * NH), 256, 0, stream>>>(Qw, Kw, Vw, Ow);

  gemm_proj<<<dim3(1024 / 128, 4096 / 128), 256, 0, stream>>>(
      Ow, wprojT, 1024, b_proj, out);
}